// Round 3
// baseline (1629.163 us; speedup 1.0000x reference)
//
#include <hip/hip_runtime.h>

// Attention_26250840113588 — round 3: dtype fix. Device buffers are FLOAT32
// (reference dtypes). Compute uses bf16 MFMA internally; fp32->bf16 conversion
// fused into LDS staging. ws holds only Q/O (bf16, in-place, 33.5 MB).
// Pipeline: gemm_bt<0,1> (Q=x@wq^T*rope, bf16 out) -> attn_fwd (in-place)
//           -> gemm_bt<1,0> (out=O@wo^T, fp32 out)

typedef __attribute__((ext_vector_type(8))) __bf16 bf16x8;
typedef __attribute__((ext_vector_type(4))) float f32x4;

#define S_LEN 2048
#define DMODEL 4096
#define NKV 8
#define HD 128

__device__ __forceinline__ bf16x8 cvt8(const float* __restrict__ p) {
  float4 f0 = *(const float4*)p, f1 = *(const float4*)(p + 4);
  bf16x8 v;
  v[0] = (__bf16)f0.x; v[1] = (__bf16)f0.y; v[2] = (__bf16)f0.z; v[3] = (__bf16)f0.w;
  v[4] = (__bf16)f1.x; v[5] = (__bf16)f1.y; v[6] = (__bf16)f1.z; v[7] = (__bf16)f1.w;
  return v;
}

// ---------------- GEMM: C[M,N] = A[M,K] @ Bw[N,K]^T (M=N=K=4096) ----------------
// A_BF16: A is bf16 (ws buffer) else fp32 (converted during staging). Bw is fp32.
// EPI==1: C is bf16, fused rope scale C[row,col] *= freqs[(row%2048)*64 + (col&63)]
// EPI==0: C is fp32 (final output).
template <int A_BF16, int EPI>
__global__ __launch_bounds__(256) void gemm_bt(
    const void* __restrict__ Av, const float* __restrict__ Bw,
    void* __restrict__ Cv, const float* __restrict__ freqs) {
  __shared__ __attribute__((aligned(16))) __bf16 As[128 * 72];  // [m][k] stride 72
  __shared__ __attribute__((aligned(16))) __bf16 Bs[128 * 72];  // [n][k] stride 72
  const int t = threadIdx.x;
  const int wave = t >> 6, lane = t & 63;
  const int l15 = lane & 15, quad = lane >> 4;
  const int wm = wave >> 1, wn = wave & 1;
  const int m0 = blockIdx.y * 128, n0 = blockIdx.x * 128;
  f32x4 acc[4][4] = {};
  for (int k0 = 0; k0 < DMODEL; k0 += 64) {
#pragma unroll
    for (int i = 0; i < 4; ++i) {  // 128 rows x 64 cols, 8 elems/thread
      int c = i * 256 + t;
      int r = c >> 3, col8 = (c & 7) * 8;
      if (A_BF16) {
        *(float4*)&As[r * 72 + col8] =
            *(const float4*)&((const __bf16*)Av)[(size_t)(m0 + r) * DMODEL + k0 + col8];
      } else {
        *(bf16x8*)&As[r * 72 + col8] =
            cvt8(&((const float*)Av)[(size_t)(m0 + r) * DMODEL + k0 + col8]);
      }
      *(bf16x8*)&Bs[r * 72 + col8] =
          cvt8(&Bw[(size_t)(n0 + r) * DMODEL + k0 + col8]);
    }
    __syncthreads();
#pragma unroll
    for (int ks = 0; ks < 2; ++ks) {
      bf16x8 af[4], bfr[4];
#pragma unroll
      for (int i = 0; i < 4; ++i) {
        af[i]  = *(const bf16x8*)&As[(wm * 64 + i * 16 + l15) * 72 + ks * 32 + quad * 8];
        bfr[i] = *(const bf16x8*)&Bs[(wn * 64 + i * 16 + l15) * 72 + ks * 32 + quad * 8];
      }
#pragma unroll
      for (int mi = 0; mi < 4; ++mi)
#pragma unroll
        for (int ni = 0; ni < 4; ++ni)
          acc[mi][ni] = __builtin_amdgcn_mfma_f32_16x16x32_bf16(
              af[mi], bfr[ni], acc[mi][ni], 0, 0, 0);
    }
    __syncthreads();
  }
#pragma unroll
  for (int mi = 0; mi < 4; ++mi) {
    int rowb = m0 + wm * 64 + mi * 16 + quad * 4;
#pragma unroll
    for (int ni = 0; ni < 4; ++ni) {
      int col = n0 + wn * 64 + ni * 16 + l15;
#pragma unroll
      for (int r = 0; r < 4; ++r) {
        float v = acc[mi][ni][r];
        if (EPI == 1) {
          int s = (rowb + r) & (S_LEN - 1);
          v *= freqs[s * 64 + (col & 63)];
          ((__bf16*)Cv)[(size_t)(rowb + r) * DMODEL + col] = (__bf16)v;
        } else {
          ((float*)Cv)[(size_t)(rowb + r) * DMODEL + col] = v;
        }
      }
    }
  }
}

// ---------------- Flash attention (causal, GQA), Q/O in-place bf16 ----------------
// Block: (qt, h, b); 4 waves x 16 q-rows. KV tiles of 64, only kt <= qt.
// QO (bf16, ws) is (B,S,NH,HD): block reads its exclusive Q slice at start,
// writes O to the same slice at end. K,V are fp32 globals (cache_k/cache_v),
// converted to bf16 during LDS staging (V transposed in the same pass).
__global__ __launch_bounds__(256) void attn_fwd(
    __bf16* __restrict__ QO, const float* __restrict__ K,
    const float* __restrict__ V) {
  __shared__ __attribute__((aligned(16))) __bf16 Ks[64 * 136];   // [kv][hd] stride 136
  __shared__ __attribute__((aligned(16))) __bf16 Vs[128 * 72];   // [hd][kv] stride 72
  __shared__ __attribute__((aligned(16))) __bf16 Ps[4][16 * 72]; // per-wave [q][kv]
  const int qt = blockIdx.x, h = blockIdx.y, b = blockIdx.z;
  const int g = h >> 2;  // NREP = 4
  const int t = threadIdx.x, wave = t >> 6, lane = t & 63;
  const int l15 = lane & 15, quad = lane >> 4;
  __bf16* qbase =
      QO + (size_t)(b * S_LEN + qt * 64 + wave * 16 + l15) * DMODEL + h * HD;
  bf16x8 qf[4];
#pragma unroll
  for (int kk = 0; kk < 4; ++kk) qf[kk] = *(const bf16x8*)&qbase[kk * 32 + quad * 8];
  f32x4 of[8] = {};
  float m_r[4], l_r[4];
#pragma unroll
  for (int r = 0; r < 4; ++r) { m_r[r] = -1e30f; l_r[r] = 0.f; }
  const float* kbase = K + ((size_t)b * S_LEN * NKV + g) * HD;
  const float* vbase = V + ((size_t)b * S_LEN * NKV + g) * HD;
  const float scale = 0.08838834764831845f;  // 1/sqrt(128)
  for (int kt = 0; kt <= qt; ++kt) {
    // stage K tile: 64 rows(kv) x 128 cols(hd), fp32 -> bf16
#pragma unroll
    for (int i = 0; i < 4; ++i) {
      int c = i * 256 + t, r = c >> 4, col8 = (c & 15) * 8;
      *(bf16x8*)&Ks[r * 136 + col8] =
          cvt8(&kbase[(size_t)(kt * 64 + r) * (NKV * HD) + col8]);
    }
    // stage V tile TRANSPOSED: read [kv][hd] coalesced fp32, write bf16 Vs[hd][kv]
#pragma unroll
    for (int i = 0; i < 4; ++i) {
      int c = i * 256 + t, r = c >> 4, col8 = (c & 15) * 8;
      bf16x8 vv = cvt8(&vbase[(size_t)(kt * 64 + r) * (NKV * HD) + col8]);
#pragma unroll
      for (int j = 0; j < 8; ++j) Vs[(col8 + j) * 72 + r] = vv[j];
    }
    __syncthreads();
    // S = Q K^T  (wave: 16 q-rows x 64 kv-cols)
    f32x4 sf[4] = {};
#pragma unroll
    for (int kk = 0; kk < 4; ++kk)
#pragma unroll
      for (int ni = 0; ni < 4; ++ni) {
        bf16x8 kf = *(const bf16x8*)&Ks[(ni * 16 + l15) * 136 + kk * 32 + quad * 8];
        sf[ni] = __builtin_amdgcn_mfma_f32_16x16x32_bf16(qf[kk], kf, sf[ni], 0, 0, 0);
      }
    // online softmax per row (row quad*4+r lives in lanes quad*16 + 0..15)
    const int rowg = qt * 64 + wave * 16 + quad * 4;
#pragma unroll
    for (int r = 0; r < 4; ++r) {
      float sv[4];
#pragma unroll
      for (int ni = 0; ni < 4; ++ni) {
        float v = sf[ni][r] * scale;
        int col = kt * 64 + ni * 16 + l15;
        if (col > rowg + r) v = -1e9f;  // causal mask (== ref's -1e9 add)
        sv[ni] = v;
      }
      float mx = fmaxf(fmaxf(sv[0], sv[1]), fmaxf(sv[2], sv[3]));
#pragma unroll
      for (int off = 1; off < 16; off <<= 1) mx = fmaxf(mx, __shfl_xor(mx, off, 64));
      float mn = fmaxf(m_r[r], mx);
      float alpha = __expf(m_r[r] - mn);
      float sum = 0.f;
#pragma unroll
      for (int ni = 0; ni < 4; ++ni) {
        float p = __expf(sv[ni] - mn);
        sum += p;
        sf[ni][r] = p;
      }
#pragma unroll
      for (int off = 1; off < 16; off <<= 1) sum += __shfl_xor(sum, off, 64);
      l_r[r] = l_r[r] * alpha + sum;
      m_r[r] = mn;
#pragma unroll
      for (int nf = 0; nf < 8; ++nf) of[nf][r] *= alpha;
    }
    // P: C-layout -> per-wave LDS -> A-operand layout
#pragma unroll
    for (int ni = 0; ni < 4; ++ni)
#pragma unroll
      for (int r = 0; r < 4; ++r)
        Ps[wave][(quad * 4 + r) * 72 + ni * 16 + l15] = (__bf16)sf[ni][r];
    asm volatile("s_waitcnt lgkmcnt(0)" ::: "memory");
    // O += P V   (B-frag: Vs[hd][kv], k(=kv)-contiguous)
#pragma unroll
    for (int kb = 0; kb < 2; ++kb) {
      bf16x8 pf = *(const bf16x8*)&Ps[wave][l15 * 72 + kb * 32 + quad * 8];
#pragma unroll
      for (int nf = 0; nf < 8; ++nf) {
        bf16x8 vf = *(const bf16x8*)&Vs[(nf * 16 + l15) * 72 + kb * 32 + quad * 8];
        of[nf] = __builtin_amdgcn_mfma_f32_16x16x32_bf16(pf, vf, of[nf], 0, 0, 0);
      }
    }
    __syncthreads();
  }
  // write O over Q (same exclusive slice)
#pragma unroll
  for (int r = 0; r < 4; ++r) {
    float inv = 1.0f / l_r[r];
    size_t row = (size_t)(b * S_LEN + qt * 64 + wave * 16 + quad * 4 + r);
#pragma unroll
    for (int nf = 0; nf < 8; ++nf)
      QO[row * DMODEL + h * HD + nf * 16 + l15] = (__bf16)(of[nf][r] * inv);
  }
}

extern "C" void kernel_launch(void* const* d_in, const int* in_sizes, int n_in,
                              void* d_out, int out_size, void* d_ws, size_t ws_size,
                              hipStream_t stream) {
  const float* x     = (const float*)d_in[0];
  const float* freqs = (const float*)d_in[1];
  // d_in[2] mask: applied analytically (triu(-1e9, k=1) == causal)
  const float* wq = (const float*)d_in[3];
  // d_in[4] wk, d_in[5] wv: dead in the reference forward (cache never written)
  const float* wo = (const float*)d_in[6];
  const float* ck = (const float*)d_in[7];
  const float* cv = (const float*)d_in[8];

  __bf16* q_ws = (__bf16*)d_ws;  // (B,S,NH,HD) bf16 = 33.5 MB (only ws use)

  gemm_bt<0, 1><<<dim3(32, 32), 256, 0, stream>>>(x, wq, q_ws, freqs);
  attn_fwd<<<dim3(32, 32, 2), 256, 0, stream>>>(q_ws, ck, cv);
  gemm_bt<1, 0><<<dim3(32, 32), 256, 0, stream>>>(q_ws, wo, (float*)d_out, nullptr);
}